// Round 1
// baseline (886.387 us; speedup 1.0000x reference)
//
#include <hip/hip_runtime.h>
#include <math.h>

#define NQ 11
#define NSTATE 2048           // 2^11
#define TSTEPS 48
#define FEAT 60
#define BATCH 128
#define BLOCK 256
#define APT (NSTATE / BLOCK)  // amplitudes per thread = 8
#define PPT (NSTATE / 2 / BLOCK) // pairs per thread = 4
#define NWAVES (BLOCK / 64)
#define TWO_PI_F 6.2831853071795864769f

struct Cx { float r, i; };
__device__ __forceinline__ Cx cmul(Cx a, Cx b){ return {a.r*b.r - a.i*b.i, a.r*b.i + a.i*b.r}; }
__device__ __forceinline__ Cx cadd(Cx a, Cx b){ return {a.r+b.r, a.i+b.i}; }

// D = A @ B (2x2 complex, row-major [00,01,10,11])
__device__ __forceinline__ void mm2(const Cx A[4], const Cx B[4], Cx D[4]) {
  D[0] = cadd(cmul(A[0],B[0]), cmul(A[1],B[2]));
  D[1] = cadd(cmul(A[0],B[1]), cmul(A[1],B[3]));
  D[2] = cadd(cmul(A[2],B[0]), cmul(A[3],B[2]));
  D[3] = cadd(cmul(A[2],B[1]), cmul(A[3],B[3]));
}

// Apply 2x2 complex unitary u (8 floats) on state bit nb. One __syncthreads at end.
__device__ __forceinline__ void apply1q(float* sre, float* sim, const float* u,
                                        int nb, int tid) {
  const float u00r=u[0],u00i=u[1],u01r=u[2],u01i=u[3],
              u10r=u[4],u10i=u[5],u11r=u[6],u11i=u[7];
  #pragma unroll
  for (int k = 0; k < PPT; ++k) {
    int p  = tid + BLOCK*k;                       // pair index 0..1023
    int lo = p & ((1<<nb)-1);
    int i0 = ((p >> nb) << (nb+1)) | lo;
    int i1 = i0 | (1<<nb);
    float a0r=sre[i0], a0i=sim[i0], a1r=sre[i1], a1i=sim[i1];
    sre[i0] = u00r*a0r - u00i*a0i + u01r*a1r - u01i*a1i;
    sim[i0] = u00r*a0i + u00i*a0r + u01r*a1i + u01i*a1r;
    sre[i1] = u10r*a0r - u10i*a0i + u11r*a1r - u11i*a1i;
    sim[i1] = u10r*a0i + u10i*a0r + u11r*a1i + u11i*a1r;
  }
  __syncthreads();
}

// Controlled-RX: control bit cb, target bit tb, RX = [[c,-is],[-is,c]]
__device__ __forceinline__ void applyCRX(float* sre, float* sim, float c, float s,
                                         int cb, int tb, int tid) {
  #pragma unroll
  for (int k = 0; k < PPT; ++k) {
    int p  = tid + BLOCK*k;
    int lo = p & ((1<<tb)-1);
    int i0 = ((p >> tb) << (tb+1)) | lo;
    if (i0 & (1<<cb)) {
      int i1 = i0 | (1<<tb);
      float a0r=sre[i0], a0i=sim[i0], a1r=sre[i1], a1i=sim[i1];
      sre[i0] = c*a0r + s*a1i;
      sim[i0] = c*a0i - s*a1r;
      sre[i1] = c*a1r + s*a0i;
      sim[i1] = c*a1i - s*a0r;
    }
  }
  __syncthreads();
}

__global__ __launch_bounds__(BLOCK)
void qrnn_kernel(const float* __restrict__ x, const float* __restrict__ hin,
                 const float* __restrict__ params, float* __restrict__ out) {
  const int b   = blockIdx.x;
  const int tid = threadIdx.x;

  __shared__ float sre[NSTATE], sim[NSTATE];
  __shared__ float Ug[22][8];       // fused RZ*RY*RX per (layer, qubit)
  __shared__ float crxc[8], crxs[8];// cos/sin(theta/2) per (layer, crx-index)
  __shared__ float pooled[6];
  __shared__ float hiddenS[5];
  __shared__ float cq[NQ], sq[NQ];  // per-step embed half-angle trig
  __shared__ float wred[NWAVES][NQ];

  // ---- one-time setup: fuse the time-invariant param gates ----
  if (tid < 22) {
    int l = tid / 11, k = tid % 11;
    int base = 37 * l;
    int off = (k < 5) ? (base + 3*k) : (base + 19 + 3*(k-5));
    float px = params[off], py = params[off+1], pz = params[off+2];
    float cx = cosf(0.5f*px), sx = sinf(0.5f*px);
    float cy = cosf(0.5f*py), sy = sinf(0.5f*py);
    float cz = cosf(0.5f*pz), sz = sinf(0.5f*pz);
    Cx RX[4] = {{cx,0.f},{0.f,-sx},{0.f,-sx},{cx,0.f}};
    Cx RY[4] = {{cy,0.f},{-sy,0.f},{sy,0.f},{cy,0.f}};
    Cx RZ[4] = {{cz,-sz},{0.f,0.f},{0.f,0.f},{cz,sz}};
    Cx M[4], U[4];
    mm2(RY, RX, M);     // applied RX first, then RY
    mm2(RZ, M,  U);     // then RZ
    Ug[tid][0]=U[0].r; Ug[tid][1]=U[0].i;
    Ug[tid][2]=U[1].r; Ug[tid][3]=U[1].i;
    Ug[tid][4]=U[2].r; Ug[tid][5]=U[2].i;
    Ug[tid][6]=U[3].r; Ug[tid][7]=U[3].i;
  } else if (tid < 30) {
    int j = tid - 22; int l = j / 4, i = j % 4;
    float th = params[37*l + 15 + i];
    crxc[j] = cosf(0.5f*th);
    crxs[j] = sinf(0.5f*th);
  }
  if (tid < 5) hiddenS[tid] = hin[b*5 + tid];
  __syncthreads();

  #pragma unroll 1
  for (int t = 0; t < TSTEPS; ++t) {
    // ---- preprocess: 6 window means, min-max scale to [0, 2pi] ----
    if (tid < 6) {
      const float* xp = x + (size_t)b*(TSTEPS*FEAT) + t*FEAT + tid*10;
      float s = 0.f;
      #pragma unroll
      for (int f = 0; f < 10; ++f) s += xp[f];
      pooled[tid] = s * 0.1f;
    }
    __syncthreads();
    if (tid < NQ) {
      float ang;
      if (tid < 5) {
        ang = hiddenS[tid];
      } else {
        float mn = pooled[0], mx = pooled[0];
        #pragma unroll
        for (int v = 1; v < 6; ++v) { mn = fminf(mn, pooled[v]); mx = fmaxf(mx, pooled[v]); }
        ang = TWO_PI_F * (pooled[tid-5] - mn) / (mx - mn + 1e-8f);
      }
      cq[tid] = cosf(0.5f*ang);
      sq[tid] = sinf(0.5f*ang);
    }
    __syncthreads();

    // ---- embed product state: amp(i) = prod_q (bit? s_q : c_q) * (-i)^popc(i) ----
    #pragma unroll
    for (int k = 0; k < APT; ++k) {
      int i = tid + BLOCK*k;
      float r = 1.f;
      #pragma unroll
      for (int q = 0; q < NQ; ++q)
        r *= ((i >> (10-q)) & 1) ? sq[q] : cq[q];
      int pc = __popc(i) & 3;
      sre[i] = (pc==0) ? r : ((pc==2) ? -r : 0.f);
      sim[i] = (pc==1) ? -r : ((pc==3) ? r : 0.f);
    }
    __syncthreads();

    // ---- circuit: 2 layers x (5 fused 1q + 4 CRX + 6 fused 1q) ----
    #pragma unroll 1
    for (int l = 0; l < 2; ++l) {
      #pragma unroll 1
      for (int q = 0; q < 5; ++q)
        apply1q(sre, sim, &Ug[l*11 + q][0], 10-q, tid);
      #pragma unroll 1
      for (int i = 0; i < 4; ++i)
        applyCRX(sre, sim, crxc[l*4+i], crxs[l*4+i], 10-i, 9-i, tid);
      #pragma unroll 1
      for (int q = 5; q < 11; ++q)
        apply1q(sre, sim, &Ug[l*11 + q][0], 10-q, tid);
    }

    // ---- <Z_q> expectations ----
    float z[NQ];
    #pragma unroll
    for (int q = 0; q < NQ; ++q) z[q] = 0.f;
    #pragma unroll
    for (int k = 0; k < APT; ++k) {
      int i = tid + BLOCK*k;
      float pr = sre[i]*sre[i] + sim[i]*sim[i];
      #pragma unroll
      for (int q = 0; q < NQ; ++q)
        z[q] += ((i >> (10-q)) & 1) ? -pr : pr;
    }
    #pragma unroll
    for (int m = 1; m < 64; m <<= 1) {
      #pragma unroll
      for (int q = 0; q < NQ; ++q)
        z[q] += __shfl_xor(z[q], m, 64);
    }
    int wid = tid >> 6;
    if ((tid & 63) == 0) {
      #pragma unroll
      for (int q = 0; q < NQ; ++q) wred[wid][q] = z[q];
    }
    __syncthreads();
    if (tid < NQ) {
      float zz = 0.f;
      #pragma unroll
      for (int w = 0; w < NWAVES; ++w) zz += wred[w][tid];
      if (tid < 5) {
        hiddenS[tid] = zz;                       // feeds next step's angles
        if (t == TSTEPS-1)
          out[BATCH*TSTEPS*6 + b*5 + tid] = zz;  // hidden_final
      } else {
        out[(size_t)b*(TSTEPS*6) + t*6 + (tid-5)] = zz;  // outputs[b,t,:]
      }
    }
    // next iteration's first two __syncthreads cover all remaining hazards
  }
}

extern "C" void kernel_launch(void* const* d_in, const int* in_sizes, int n_in,
                              void* d_out, int out_size, void* d_ws, size_t ws_size,
                              hipStream_t stream) {
  const float* x      = (const float*)d_in[0];
  const float* hidden = (const float*)d_in[1];
  const float* params = (const float*)d_in[2];
  float* out          = (float*)d_out;
  qrnn_kernel<<<dim3(BATCH), dim3(BLOCK), 0, stream>>>(x, hidden, params, out);
}

// Round 2
// 418.607 us; speedup vs baseline: 2.1175x; 2.1175x over previous
//
#include <hip/hip_runtime.h>
#include <math.h>

#define NQ 11
#define TSTEPS 48
#define FEAT 60
#define BATCH 128
#define BLOCK 256
#define TWO_PI_F 6.2831853071795864769f

// State-bit mapping (index i, bit b holds qubit 10-b):
//   bits 9,8,7 -> register index r (8 float2 amps per thread)
//   bits 6..1  -> lane bits 5..0   (gates via shfl_xor, no barrier)
//   bits 10,0  -> wave bits 1,0    (gates via LDS exchange + 1 barrier)
// Per layer: CRX(c q_i, t q_{i+1}) fused into target's 1q gate as matrix
// select U vs V=RX*U by the control bit (wave-uniform for b9, compile-time
// per register pair for b8/b7, compile-time per amp for b6).

__device__ __forceinline__ float rlane(float v, int l) {
  return __int_as_float(__builtin_amdgcn_readlane(__float_as_int(v), l));
}

struct Cf { float r, i; };
__device__ __forceinline__ Cf cmul(Cf a, Cf b){ return {a.r*b.r - a.i*b.i, a.r*b.i + a.i*b.r}; }
__device__ __forceinline__ Cf cadd(Cf a, Cf b){ return {a.r+b.r, a.i+b.i}; }
__device__ __forceinline__ void mm2(const Cf A[4], const Cf B[4], Cf D[4]) {
  D[0] = cadd(cmul(A[0],B[0]), cmul(A[1],B[2]));
  D[1] = cadd(cmul(A[0],B[1]), cmul(A[1],B[3]));
  D[2] = cadd(cmul(A[2],B[0]), cmul(A[3],B[2]));
  D[3] = cadd(cmul(A[2],B[1]), cmul(A[3],B[3]));
}

// ---- in-register gate on reg bit K; per-pair matrix select by reg bit CTRL (-1: none)
template<int K, int CTRL>
__device__ __forceinline__ void gate_reg(float2 a[8], const float* U, const float* V) {
  float4 u0 = *(const float4*)U, u1 = *(const float4*)(U+4);
  float4 v0 = u0, v1 = u1;
  if (CTRL >= 0) { v0 = *(const float4*)V; v1 = *(const float4*)(V+4); }
  #pragma unroll
  for (int r0 = 0; r0 < 8; ++r0) {
    if (r0 & (1<<K)) continue;
    const int r1 = r0 | (1<<K);
    const bool useV = (CTRL >= 0) && ((r0 >> CTRL) & 1);
    float4 m0 = useV ? v0 : u0, m1 = useV ? v1 : u1;   // compile-time select
    float2 A = a[r0], B = a[r1];
    a[r0].x = m0.x*A.x - m0.y*A.y + m0.z*B.x - m0.w*B.y;
    a[r0].y = m0.x*A.y + m0.y*A.x + m0.z*B.y + m0.w*B.x;
    a[r1].x = m1.x*A.x - m1.y*A.y + m1.z*B.x - m1.w*B.y;
    a[r1].y = m1.x*A.y + m1.y*A.x + m1.z*B.y + m1.w*B.x;
  }
}

// ---- cross-lane gate on lane bit LB (state bit LB+1); per-amp select by reg bit CTRL
template<int LB, int CTRL>
__device__ __forceinline__ void gate_lane(float2 a[8], const float* U, const float* V, int lane) {
  const int bit = (lane >> LB) & 1;
  float4 u0 = *(const float4*)U, u1 = *(const float4*)(U+4);
  // row select: bit==0: new = u00*a + u01*p ; bit==1: new = u11*a + u10*p
  float um0r = bit ? u1.z : u0.x, um0i = bit ? u1.w : u0.y;
  float um1r = bit ? u1.x : u0.z, um1i = bit ? u1.y : u0.w;
  float vm0r = um0r, vm0i = um0i, vm1r = um1r, vm1i = um1i;
  if (CTRL >= 0) {
    float4 w0 = *(const float4*)V, w1 = *(const float4*)(V+4);
    vm0r = bit ? w1.z : w0.x; vm0i = bit ? w1.w : w0.y;
    vm1r = bit ? w1.x : w0.z; vm1i = bit ? w1.y : w0.w;
  }
  #pragma unroll
  for (int r = 0; r < 8; ++r) {
    const bool useV = (CTRL >= 0) && ((r >> CTRL) & 1);
    float m0r = useV ? vm0r : um0r, m0i = useV ? vm0i : um0i;
    float m1r = useV ? vm1r : um1r, m1i = useV ? vm1i : um1i;
    float px = __shfl_xor(a[r].x, 1<<LB, 64);
    float py = __shfl_xor(a[r].y, 1<<LB, 64);
    float ax = a[r].x, ay = a[r].y;
    a[r].x = m0r*ax - m0i*ay + m1r*px - m1i*py;
    a[r].y = m0r*ay + m0i*ax + m1r*py + m1i*px;
  }
}

// ---- cross-wave gate on wave bit WB (state bit: WB?10:0) via LDS exchange
template<int WB>
__device__ __forceinline__ void gate_wave(float2 a[8], const float* U, float2* buf, int tid) {
  #pragma unroll
  for (int r = 0; r < 8; ++r) buf[(r<<8) + tid] = a[r];
  __syncthreads();
  const int pt = tid ^ (64 << WB);
  const int bit = (tid >> (6+WB)) & 1;
  float4 u0 = *(const float4*)U, u1 = *(const float4*)(U+4);
  float m0r = bit ? u1.z : u0.x, m0i = bit ? u1.w : u0.y;
  float m1r = bit ? u1.x : u0.z, m1i = bit ? u1.y : u0.w;
  #pragma unroll
  for (int r = 0; r < 8; ++r) {
    float2 p = buf[(r<<8) + pt];
    float ax = a[r].x, ay = a[r].y;
    a[r].x = m0r*ax - m0i*ay + m1r*p.x - m1i*p.y;
    a[r].y = m0r*ay + m0i*ax + m1r*p.y + m1i*p.x;
  }
}

__global__ __launch_bounds__(BLOCK, 1)
void qrnn_kernel(const float* __restrict__ x, const float* __restrict__ hin,
                 const float* __restrict__ params, float* __restrict__ out) {
  const int b    = blockIdx.x;
  const int tid  = threadIdx.x;
  const int lane = tid & 63;
  const int w    = tid >> 6;
  const int w0   = w & 1, w1 = (w >> 1) & 1;

  __shared__ __align__(16) float matU[2][11][8];
  __shared__ __align__(16) float matV[2][4][8];
  __shared__ float  xs[TSTEPS*FEAT];         // 11520 B
  __shared__ float2 xbuf[2][2048];           // 32768 B, double-buffered exchange
  __shared__ float  wred[4][10];

  // ---- setup: fused per-(layer,qubit) matrices U = RZ*RY*RX ----
  if (tid < 22) {
    int l = tid / 11, k = tid % 11;
    int base = 37 * l;
    int off = (k < 5) ? (base + 3*k) : (base + 19 + 3*(k-5));
    float px = params[off], py = params[off+1], pz = params[off+2];
    float cx = cosf(0.5f*px), sx = sinf(0.5f*px);
    float cy = cosf(0.5f*py), sy = sinf(0.5f*py);
    float cz = cosf(0.5f*pz), sz = sinf(0.5f*pz);
    Cf RX[4] = {{cx,0.f},{0.f,-sx},{0.f,-sx},{cx,0.f}};
    Cf RY[4] = {{cy,0.f},{-sy,0.f},{sy,0.f},{cy,0.f}};
    Cf RZ[4] = {{cz,-sz},{0.f,0.f},{0.f,0.f},{cz,sz}};
    Cf M[4], U[4];
    mm2(RY, RX, M);
    mm2(RZ, M,  U);
    float* d = &matU[l][k][0];
    d[0]=U[0].r; d[1]=U[0].i; d[2]=U[1].r; d[3]=U[1].i;
    d[4]=U[2].r; d[5]=U[2].i; d[6]=U[3].r; d[7]=U[3].i;
  }
  __syncthreads();
  // V[l][i] = RX(theta_crx_i) * U[l][qubit i+1]  (CRX target-fused variant)
  if (tid < 8) {
    int l = tid >> 2, i = tid & 3;
    float th = params[37*l + 15 + i];
    float c = cosf(0.5f*th), s = sinf(0.5f*th);
    const float* Up = &matU[l][i+1][0];
    Cf U00{Up[0],Up[1]}, U01{Up[2],Up[3]}, U10{Up[4],Up[5]}, U11{Up[6],Up[7]};
    Cf ms{0.f, -s};
    Cf V00 = cadd(Cf{c*U00.r, c*U00.i}, cmul(ms, U10));
    Cf V01 = cadd(Cf{c*U01.r, c*U01.i}, cmul(ms, U11));
    Cf V10 = cadd(cmul(ms, U00), Cf{c*U10.r, c*U10.i});
    Cf V11 = cadd(cmul(ms, U01), Cf{c*U11.r, c*U11.i});
    float* d = &matV[l][i][0];
    d[0]=V00.r; d[1]=V00.i; d[2]=V01.r; d[3]=V01.i;
    d[4]=V10.r; d[5]=V10.i; d[6]=V11.r; d[7]=V11.i;
  }
  // cache this block's whole x[b] (48x60) in LDS, coalesced
  for (int j = tid; j < TSTEPS*FEAT; j += BLOCK)
    xs[j] = x[(size_t)b*TSTEPS*FEAT + j];
  float h0 = hin[b*5+0], h1 = hin[b*5+1], h2 = hin[b*5+2],
        h3 = hin[b*5+3], h4 = hin[b*5+4];
  __syncthreads();

  const int pu = __popc(lane) + w0 + w1;   // thread-uniform popcount part

  #pragma unroll 1
  for (int t = 0; t < TSTEPS; ++t) {
    // ---- preprocess (replicated per wave, no barrier) ----
    float pooled = 0.f;
    if (lane < 6) {
      const float* xp = &xs[t*FEAT + lane*10];
      #pragma unroll
      for (int f = 0; f < 10; ++f) pooled += xp[f];
      pooled *= 0.1f;
    }
    float p0 = rlane(pooled,0), p1 = rlane(pooled,1), p2 = rlane(pooled,2);
    float p3 = rlane(pooled,3), p4 = rlane(pooled,4), p5 = rlane(pooled,5);
    float mn = fminf(fminf(fminf(p0,p1),fminf(p2,p3)),fminf(p4,p5));
    float mx = fmaxf(fmaxf(fmaxf(p0,p1),fmaxf(p2,p3)),fmaxf(p4,p5));
    float ang;
    if (lane < 5) {
      ang = (lane==0)?h0:(lane==1)?h1:(lane==2)?h2:(lane==3)?h3:h4;
    } else {
      float ps = (lane==5)?p0:(lane==6)?p1:(lane==7)?p2:(lane==8)?p3:(lane==9)?p4:p5;
      ang = TWO_PI_F * (ps - mn) / (mx - mn + 1e-8f);
    }
    float ch = __cosf(0.5f*ang), sh = __sinf(0.5f*ang);
    float cb[11], sb[11];          // per state-bit b: qubit 10-b => lane 10-b
    #pragma unroll
    for (int bb = 0; bb < 11; ++bb) { cb[bb] = rlane(ch, 10-bb); sb[bb] = rlane(sh, 10-bb); }

    // ---- embed product state into registers ----
    float F = (w1 ? sb[10] : cb[10]) * (w0 ? sb[0] : cb[0]);
    #pragma unroll
    for (int bb = 1; bb <= 6; ++bb) F *= ((lane >> (bb-1)) & 1) ? sb[bb] : cb[bb];
    float e9[2] = {cb[9], sb[9]}, e8[2] = {cb[8], sb[8]}, e7[2] = {cb[7], sb[7]};
    float2 a[8];
    #pragma unroll
    for (int r = 0; r < 8; ++r) {
      float m = F * e9[(r>>2)&1] * e8[(r>>1)&1] * e7[r&1];
      int c = (pu + __popc(r)) & 3;  // amp = m * (-i)^popc
      a[r].x = (c==0) ? m : ((c==2) ? -m : 0.f);
      a[r].y = (c==1) ? -m : ((c==3) ? m : 0.f);
    }

    // ---- circuit: 2 layers, 11 fused passes each ----
    #pragma unroll 1
    for (int l = 0; l < 2; ++l) {
      gate_wave<1>(a, &matU[l][0][0], &xbuf[0][0], tid);                 // b10 q0
      { const float* M9 = (w & 2) ? &matV[l][0][0] : &matU[l][1][0];     // b9 q1 (+CRX c b10)
        gate_reg<2,-1>(a, M9, M9); }
      gate_reg<1, 2>(a, &matU[l][2][0], &matV[l][1][0]);                 // b8 q2 (+CRX c b9)
      gate_reg<0, 1>(a, &matU[l][3][0], &matV[l][2][0]);                 // b7 q3 (+CRX c b8)
      gate_lane<5, 0>(a, &matU[l][4][0], &matV[l][3][0], lane);          // b6 q4 (+CRX c b7)
      gate_lane<4,-1>(a, &matU[l][5][0], &matU[l][5][0], lane);          // b5 q5
      gate_lane<3,-1>(a, &matU[l][6][0], &matU[l][6][0], lane);          // b4 q6
      gate_lane<2,-1>(a, &matU[l][7][0], &matU[l][7][0], lane);          // b3 q7
      gate_lane<1,-1>(a, &matU[l][8][0], &matU[l][8][0], lane);          // b2 q8
      gate_lane<0,-1>(a, &matU[l][9][0], &matU[l][9][0], lane);          // b1 q9
      gate_wave<0>(a, &matU[l][10][0], &xbuf[1][0], tid);                // b0 q10
    }

    // ---- <Z> expectations: per-thread partials + signed butterfly ----
    float S = 0.f, Z9 = 0.f, Z8 = 0.f, Z7 = 0.f;
    #pragma unroll
    for (int r = 0; r < 8; ++r) {
      float p = a[r].x*a[r].x + a[r].y*a[r].y;
      S  += p;
      Z9 += (r & 4) ? -p : p;
      Z8 += (r & 2) ? -p : p;
      Z7 += (r & 1) ? -p : p;
    }
    float v0 = S, v1 = Z9, v2 = Z8, v3 = Z7;
    float T0, T1, T2, T3, T4, T5;
    { float xx = __shfl_xor(v0, 1,64); T0 = (lane&1)? xx-v0 : v0-xx; v0 += xx;
      v1 += __shfl_xor(v1,1,64); v2 += __shfl_xor(v2,1,64); v3 += __shfl_xor(v3,1,64); }
    { float xx = __shfl_xor(v0, 2,64); T1 = (lane&2)? xx-v0 : v0-xx; v0 += xx;
      v1 += __shfl_xor(v1,2,64); v2 += __shfl_xor(v2,2,64); v3 += __shfl_xor(v3,2,64);
      T0 += __shfl_xor(T0,2,64); }
    { float xx = __shfl_xor(v0, 4,64); T2 = (lane&4)? xx-v0 : v0-xx; v0 += xx;
      v1 += __shfl_xor(v1,4,64); v2 += __shfl_xor(v2,4,64); v3 += __shfl_xor(v3,4,64);
      T0 += __shfl_xor(T0,4,64); T1 += __shfl_xor(T1,4,64); }
    { float xx = __shfl_xor(v0, 8,64); T3 = (lane&8)? xx-v0 : v0-xx; v0 += xx;
      v1 += __shfl_xor(v1,8,64); v2 += __shfl_xor(v2,8,64); v3 += __shfl_xor(v3,8,64);
      T0 += __shfl_xor(T0,8,64); T1 += __shfl_xor(T1,8,64); T2 += __shfl_xor(T2,8,64); }
    { float xx = __shfl_xor(v0,16,64); T4 = (lane&16)? xx-v0 : v0-xx; v0 += xx;
      v1 += __shfl_xor(v1,16,64); v2 += __shfl_xor(v2,16,64); v3 += __shfl_xor(v3,16,64);
      T0 += __shfl_xor(T0,16,64); T1 += __shfl_xor(T1,16,64); T2 += __shfl_xor(T2,16,64);
      T3 += __shfl_xor(T3,16,64); }
    { float xx = __shfl_xor(v0,32,64); T5 = (lane&32)? xx-v0 : v0-xx; v0 += xx;
      v1 += __shfl_xor(v1,32,64); v2 += __shfl_xor(v2,32,64); v3 += __shfl_xor(v3,32,64);
      T0 += __shfl_xor(T0,32,64); T1 += __shfl_xor(T1,32,64); T2 += __shfl_xor(T2,32,64);
      T3 += __shfl_xor(T3,32,64); T4 += __shfl_xor(T4,32,64); }

    if (lane == 0) {
      float* wr = &wred[w][0];
      wr[0]=v0; wr[1]=v1; wr[2]=v2; wr[3]=v3;
      wr[4]=T0; wr[5]=T1; wr[6]=T2; wr[7]=T3; wr[8]=T4; wr[9]=T5;
    }
    __syncthreads();
    #define SUM4(j) (wred[0][j]+wred[1][j]+wred[2][j]+wred[3][j])
    float P0 = wred[0][0], P1 = wred[1][0], P2 = wred[2][0], P3 = wred[3][0];
    float zb10 = (P0+P1) - (P2+P3);   // wave bit1 sign
    float zb0  = (P0+P2) - (P1+P3);   // wave bit0 sign
    h0 = zb10; h1 = SUM4(1); h2 = SUM4(2); h3 = SUM4(3); h4 = SUM4(9);
    float o0 = SUM4(8), o1 = SUM4(7), o2 = SUM4(6), o3 = SUM4(5), o4 = SUM4(4), o5 = zb0;
    #undef SUM4

    if (tid == 0) {
      float* op = out + (size_t)b*(TSTEPS*6) + t*6;
      op[0]=o0; op[1]=o1; op[2]=o2; op[3]=o3; op[4]=o4; op[5]=o5;
      if (t == TSTEPS-1) {
        float* hp = out + BATCH*TSTEPS*6 + b*5;
        hp[0]=h0; hp[1]=h1; hp[2]=h2; hp[3]=h3; hp[4]=h4;
      }
    }
    // wred race vs next step: next writes preceded by 4 LDS-gate barriers
  }
}

extern "C" void kernel_launch(void* const* d_in, const int* in_sizes, int n_in,
                              void* d_out, int out_size, void* d_ws, size_t ws_size,
                              hipStream_t stream) {
  const float* x      = (const float*)d_in[0];
  const float* hidden = (const float*)d_in[1];
  const float* params = (const float*)d_in[2];
  float* out          = (float*)d_out;
  qrnn_kernel<<<dim3(BATCH), dim3(BLOCK), 0, stream>>>(x, hidden, params, out);
}

// Round 3
// 267.561 us; speedup vs baseline: 3.3128x; 1.5645x over previous
//
#include <hip/hip_runtime.h>
#include <math.h>

#define TSTEPS 48
#define FEAT 60
#define BATCH 128
#define BLOCK 256
#define TWO_PI_F 6.2831853071795864769f

// State-bit mapping (index bit b holds qubit 10-b):
//   bits 9,8,7 -> register bits 2,1,0 (8 float2 amps/thread)
//   bits 6..1  -> lane bits 5..0
//   bits 10,0  -> wave bits 1,0
// Layer 1's eleven 1q gates are folded into the product-state embedding
// (per-qubit 2-vectors), leaving only the 4 CRX passes (RX-structured,
// control-bit select only -> never cross-wave). Layer 2 runs as passes with
// CRX fused into target gates (V = RX*U select by control bit).

struct Cf { float r, i; };
__device__ __forceinline__ Cf cmul(Cf a, Cf b){ return {a.r*b.r - a.i*b.i, a.r*b.i + a.i*b.r}; }
__device__ __forceinline__ Cf cadd(Cf a, Cf b){ return {a.r+b.r, a.i+b.i}; }
__device__ __forceinline__ void mm2(const Cf A[4], const Cf B[4], Cf D[4]) {
  D[0] = cadd(cmul(A[0],B[0]), cmul(A[1],B[2]));
  D[1] = cadd(cmul(A[0],B[1]), cmul(A[1],B[3]));
  D[2] = cadd(cmul(A[2],B[0]), cmul(A[3],B[2]));
  D[3] = cadd(cmul(A[2],B[1]), cmul(A[3],B[3]));
}

struct Mat { float4 r0, r1; };  // (u00r,u00i,u01r,u01i) (u10r,u10i,u11r,u11i)

__device__ __forceinline__ float rlane(float v, int l) {
  return __int_as_float(__builtin_amdgcn_readlane(__float_as_int(v), l));
}

// cross-lane xor: DPP quad_perm for masks 1,2 (VALU, no LDS pipe), else shfl
template<int M>
__device__ __forceinline__ float sx(float v) {
  if constexpr (M == 1)
    return __int_as_float(__builtin_amdgcn_mov_dpp(__float_as_int(v), 0xB1, 0xF, 0xF, true));
  else if constexpr (M == 2)
    return __int_as_float(__builtin_amdgcn_mov_dpp(__float_as_int(v), 0x4E, 0xF, 0xF, true));
  else
    return __shfl_xor(v, M, 64);
}

__device__ __forceinline__ Cf csel(float4 v, int b) {
  return b ? Cf{v.z, v.w} : Cf{v.x, v.y};
}

// RX mix on an amp pair (c - i*s structure): 4 VALU/amp
__device__ __forceinline__ void rxmix(float2& a0, float2& a1, float c, float s) {
  float n0x = c*a0.x + s*a1.y, n0y = c*a0.y - s*a1.x;
  float n1x = c*a1.x + s*a0.y, n1y = c*a1.y - s*a0.x;
  a0.x = n0x; a0.y = n0y; a1.x = n1x; a1.y = n1y;
}

// in-register gate on reg bit K; matrix select by reg bit CTRL (compile-time)
template<int K, int CTRL>
__device__ __forceinline__ void gate_reg(float2 a[8], Mat U, Mat V) {
  #pragma unroll
  for (int r0 = 0; r0 < 8; ++r0) {
    if (r0 & (1<<K)) continue;
    const int r1 = r0 | (1<<K);
    const bool useV = (CTRL >= 0) && ((r0 >> CTRL) & 1);
    float4 m0 = useV ? V.r0 : U.r0;
    float4 m1 = useV ? V.r1 : U.r1;
    float2 A = a[r0], B = a[r1];
    a[r0].x = m0.x*A.x - m0.y*A.y + m0.z*B.x - m0.w*B.y;
    a[r0].y = m0.x*A.y + m0.y*A.x + m0.z*B.y + m0.w*B.x;
    a[r1].x = m1.x*A.x - m1.y*A.y + m1.z*B.x - m1.w*B.y;
    a[r1].y = m1.x*A.y + m1.y*A.x + m1.z*B.y + m1.w*B.x;
  }
}

// cross-lane gate on lane bit LB; matrix select by reg bit CTRL
template<int LB, int CTRL>
__device__ __forceinline__ void gate_lane(float2 a[8], Mat U, Mat V, int lane) {
  const int bit = (lane >> LB) & 1;
  float um0r = bit ? U.r1.z : U.r0.x, um0i = bit ? U.r1.w : U.r0.y;
  float um1r = bit ? U.r1.x : U.r0.z, um1i = bit ? U.r1.y : U.r0.w;
  float vm0r = um0r, vm0i = um0i, vm1r = um1r, vm1i = um1i;
  if (CTRL >= 0) {
    vm0r = bit ? V.r1.z : V.r0.x; vm0i = bit ? V.r1.w : V.r0.y;
    vm1r = bit ? V.r1.x : V.r0.z; vm1i = bit ? V.r1.y : V.r0.w;
  }
  #pragma unroll
  for (int r = 0; r < 8; ++r) {
    const bool useV = (CTRL >= 0) && ((r >> CTRL) & 1);
    float m0r = useV ? vm0r : um0r, m0i = useV ? vm0i : um0i;
    float m1r = useV ? vm1r : um1r, m1i = useV ? vm1i : um1i;
    float px = sx<(1<<LB)>(a[r].x);
    float py = sx<(1<<LB)>(a[r].y);
    float ax = a[r].x, ay = a[r].y;
    a[r].x = m0r*ax - m0i*ay + m1r*px - m1i*py;
    a[r].y = m0r*ay + m0i*ax + m1r*py + m1i*px;
  }
}

// cross-wave gate on wave bit WB via LDS exchange (1 barrier)
template<int WB>
__device__ __forceinline__ void gate_wave(float2 a[8], Mat U, float2* buf, int tid) {
  #pragma unroll
  for (int r = 0; r < 8; ++r) buf[(r<<8) + tid] = a[r];
  __syncthreads();
  const int pt  = tid ^ (64 << WB);
  const int bit = (tid >> (6+WB)) & 1;
  float m0r = bit ? U.r1.z : U.r0.x, m0i = bit ? U.r1.w : U.r0.y;
  float m1r = bit ? U.r1.x : U.r0.z, m1i = bit ? U.r1.y : U.r0.w;
  #pragma unroll
  for (int r = 0; r < 8; ++r) {
    float2 p = buf[(r<<8) + pt];
    float ax = a[r].x, ay = a[r].y;
    a[r].x = m0r*ax - m0i*ay + m1r*p.x - m1i*p.y;
    a[r].y = m0r*ay + m0i*ax + m1r*p.y + m1i*p.x;
  }
}

__global__ __launch_bounds__(BLOCK, 1)
void qrnn_kernel(const float* __restrict__ x, const float* __restrict__ hin,
                 const float* __restrict__ params, float* __restrict__ out) {
  const int b    = blockIdx.x;
  const int tid  = threadIdx.x;
  const int lane = tid & 63;
  const int w    = tid >> 6;
  const int w0   = w & 1, w1 = (w >> 1) & 1;

  __shared__ __align__(16) float matU[2][11][8];
  __shared__ __align__(16) float matVs[4][8];
  __shared__ float  xs[TSTEPS*FEAT];
  __shared__ float  pooled[TSTEPS][6];
  __shared__ float4 evis[TSTEPS][6];     // visible-qubit e-vectors per step
  __shared__ float2 xbuf[2][2048];
  __shared__ float  wred[4][10];

  // ---- stage x, build fused matrices ----
  for (int j = tid; j < TSTEPS*FEAT; j += BLOCK)
    xs[j] = x[(size_t)b*TSTEPS*FEAT + j];
  if (tid < 22) {
    int l = tid / 11, k = tid % 11;
    int base = 37 * l;
    int off = (k < 5) ? (base + 3*k) : (base + 19 + 3*(k-5));
    float px = params[off], py = params[off+1], pz = params[off+2];
    float cx = cosf(0.5f*px), sxn = sinf(0.5f*px);
    float cy = cosf(0.5f*py), syn = sinf(0.5f*py);
    float cz = cosf(0.5f*pz), szn = sinf(0.5f*pz);
    Cf RX[4] = {{cx,0.f},{0.f,-sxn},{0.f,-sxn},{cx,0.f}};
    Cf RY[4] = {{cy,0.f},{-syn,0.f},{syn,0.f},{cy,0.f}};
    Cf RZ[4] = {{cz,-szn},{0.f,0.f},{0.f,0.f},{cz,szn}};
    Cf M[4], U[4];
    mm2(RY, RX, M);
    mm2(RZ, M,  U);
    float* d = &matU[l][k][0];
    d[0]=U[0].r; d[1]=U[0].i; d[2]=U[1].r; d[3]=U[1].i;
    d[4]=U[2].r; d[5]=U[2].i; d[6]=U[3].r; d[7]=U[3].i;
  }
  __syncthreads();
  // layer-2 CRX-fused variants: V[i] = RX(theta_L2,i) * U2[i+1]
  if (tid < 4) {
    float th = params[37 + 15 + tid];
    float c = cosf(0.5f*th), s = sinf(0.5f*th);
    const float* Up = &matU[1][tid+1][0];
    Cf U00{Up[0],Up[1]}, U01{Up[2],Up[3]}, U10{Up[4],Up[5]}, U11{Up[6],Up[7]};
    Cf ms{0.f, -s};
    Cf V00 = cadd(Cf{c*U00.r, c*U00.i}, cmul(ms, U10));
    Cf V01 = cadd(Cf{c*U01.r, c*U01.i}, cmul(ms, U11));
    Cf V10 = cadd(cmul(ms, U00), Cf{c*U10.r, c*U10.i});
    Cf V11 = cadd(cmul(ms, U01), Cf{c*U11.r, c*U11.i});
    float* d = &matVs[tid][0];
    d[0]=V00.r; d[1]=V00.i; d[2]=V01.r; d[3]=V01.i;
    d[4]=V10.r; d[5]=V10.i; d[6]=V11.r; d[7]=V11.i;
  }
  // window means for all steps
  for (int j = tid; j < TSTEPS*6; j += BLOCK) {
    int t = j / 6, k = j % 6;
    const float* xp = &xs[t*FEAT + k*10];
    float s = 0.f;
    #pragma unroll
    for (int f = 0; f < 10; ++f) s += xp[f];
    pooled[t][k] = s * 0.1f;
  }
  __syncthreads();
  // visible e-vectors for all steps: e = U1[5+k] * (cos(a/2), -i sin(a/2))
  for (int j = tid; j < TSTEPS*6; j += BLOCK) {
    int t = j / 6, k = j % 6;
    float mn = pooled[t][0], mx = pooled[t][0];
    #pragma unroll
    for (int v = 1; v < 6; ++v) { mn = fminf(mn, pooled[t][v]); mx = fmaxf(mx, pooled[t][v]); }
    float ang = TWO_PI_F * (pooled[t][k] - mn) / (mx - mn + 1e-8f);
    float c = __cosf(0.5f*ang), s = __sinf(0.5f*ang);
    const float* U = &matU[0][5+k][0];
    evis[t][k] = make_float4(U[0]*c + U[3]*s, U[1]*c - U[2]*s,
                             U[4]*c + U[7]*s, U[5]*c - U[6]*s);
  }

  // ---- hoist loop-invariant matrices into registers ----
  Mat mU[11], mV[4];
  #pragma unroll
  for (int q = 0; q < 11; ++q) {
    mU[q].r0 = *(const float4*)&matU[1][q][0];
    mU[q].r1 = *(const float4*)&matU[1][q][4];
  }
  // layer-1 CRX trig (raw, standalone passes)
  float c1[4], s1[4];
  #pragma unroll
  for (int i = 0; i < 4; ++i) {
    float th = params[15 + i];
    c1[i] = cosf(0.5f*th); s1[i] = sinf(0.5f*th);
  }
  // U1 row for this lane's hidden qubit (lanes 0..4)
  const int lq = (lane < 5) ? lane : 0;
  float4 mH0 = *(const float4*)&matU[0][lq][0];
  float4 mH1 = *(const float4*)&matU[0][lq][4];
  float h0 = hin[b*5+0], h1 = hin[b*5+1], h2 = hin[b*5+2],
        h3 = hin[b*5+3], h4 = hin[b*5+4];
  __syncthreads();
  #pragma unroll
  for (int i = 0; i < 4; ++i) {
    mV[i].r0 = *(const float4*)&matVs[i][0];
    mV[i].r1 = *(const float4*)&matVs[i][4];
  }

  const int l5 = (lane >> 5) & 1;

  #pragma unroll 1
  for (int t = 0; t < TSTEPS; ++t) {
    // ---- visible factor (independent of h: overlaps the trig chain) ----
    float4 v5 = evis[t][0], v6 = evis[t][1], v7 = evis[t][2],
           v8 = evis[t][3], v9 = evis[t][4], v10 = evis[t][5];
    Cf Fv = csel(v10, w0);
    Fv = cmul(Fv, csel(v5, (lane>>4)&1));
    Fv = cmul(Fv, csel(v6, (lane>>3)&1));
    Fv = cmul(Fv, csel(v7, (lane>>2)&1));
    Fv = cmul(Fv, csel(v8, (lane>>1)&1));
    Fv = cmul(Fv, csel(v9,  lane     &1));

    // ---- hidden e-vectors (lane q computes qubit q, then broadcast) ----
    float ang = (lane==0)?h0:(lane==1)?h1:(lane==2)?h2:(lane==3)?h3:h4;
    float chh = __cosf(0.5f*ang), shh = __sinf(0.5f*ang);
    float e0r = mH0.x*chh + mH0.w*shh;
    float e0i = mH0.y*chh - mH0.z*shh;
    float e1r = mH1.x*chh + mH1.w*shh;
    float e1i = mH1.y*chh - mH1.z*shh;
    float ehr[5][2], ehi[5][2];
    #pragma unroll
    for (int q = 0; q < 5; ++q) {
      ehr[q][0] = rlane(e0r, q); ehi[q][0] = rlane(e0i, q);
      ehr[q][1] = rlane(e1r, q); ehi[q][1] = rlane(e1i, q);
    }

    // ---- embed (all layer-1 1q gates folded in) ----
    Cf F = cmul(Fv, Cf{ehr[0][w1], ehi[0][w1]});     // qubit 0 (wave bit1)
    F = cmul(F, Cf{ehr[4][l5], ehi[4][l5]});          // qubit 4 (lane bit5)
    Cf E01[4];
    #pragma unroll
    for (int i = 0; i < 2; ++i)
      #pragma unroll
      for (int j = 0; j < 2; ++j)
        E01[i*2+j] = cmul(Cf{ehr[1][i],ehi[1][i]}, Cf{ehr[2][j],ehi[2][j]});
    float2 a[8];
    #pragma unroll
    for (int r = 0; r < 8; ++r) {
      Cf E = cmul(E01[r>>1], Cf{ehr[3][r&1], ehi[3][r&1]});
      Cf A = cmul(F, E);
      a[r].x = A.r; a[r].y = A.i;
    }

    // ---- layer 1: only the 4 CRX passes remain ----
    if (w1) {                                  // CRX(q0,q1): ctrl wave bit1
      #pragma unroll
      for (int r = 0; r < 4; ++r) rxmix(a[r], a[r+4], c1[0], s1[0]);
    }
    rxmix(a[4], a[6], c1[1], s1[1]);           // CRX(q1,q2): ctrl reg bit2
    rxmix(a[5], a[7], c1[1], s1[1]);
    rxmix(a[2], a[3], c1[2], s1[2]);           // CRX(q2,q3): ctrl reg bit1
    rxmix(a[6], a[7], c1[2], s1[2]);
    #pragma unroll
    for (int r = 1; r < 8; r += 2) {           // CRX(q3,q4): ctrl reg bit0, tgt lane5
      float px = __shfl_xor(a[r].x, 32, 64);
      float py = __shfl_xor(a[r].y, 32, 64);
      float ax = a[r].x, ay = a[r].y;
      a[r].x = c1[3]*ax + s1[3]*py;
      a[r].y = c1[3]*ay - s1[3]*px;
    }

    // ---- layer 2: 11 passes (CRX fused into targets) ----
    gate_wave<1>(a, mU[0], &xbuf[0][0], tid);               // q0  (wave b10)
    { Mat M9; M9.r0 = w1 ? mV[0].r0 : mU[1].r0;             // q1  (+CRX c=q0)
      M9.r1 = w1 ? mV[0].r1 : mU[1].r1;
      gate_reg<2,-1>(a, M9, M9); }
    gate_reg<1, 2>(a, mU[2], mV[1]);                        // q2  (+CRX c=q1)
    gate_reg<0, 1>(a, mU[3], mV[2]);                        // q3  (+CRX c=q2)
    gate_lane<5, 0>(a, mU[4], mV[3], lane);                 // q4  (+CRX c=q3)
    gate_lane<4,-1>(a, mU[5], mU[5], lane);                 // q5
    gate_lane<3,-1>(a, mU[6], mU[6], lane);                 // q6
    gate_lane<2,-1>(a, mU[7], mU[7], lane);                 // q7
    gate_lane<1,-1>(a, mU[8], mU[8], lane);                 // q8 (DPP)
    gate_lane<0,-1>(a, mU[9], mU[9], lane);                 // q9 (DPP)
    gate_wave<0>(a, mU[10], &xbuf[1][0], tid);              // q10 (wave b0)

    // ---- <Z> expectations ----
    float S = 0.f, Z9 = 0.f, Z8 = 0.f, Z7 = 0.f;
    #pragma unroll
    for (int r = 0; r < 8; ++r) {
      float p = a[r].x*a[r].x + a[r].y*a[r].y;
      S  += p;
      Z9 += (r & 4) ? -p : p;
      Z8 += (r & 2) ? -p : p;
      Z7 += (r & 1) ? -p : p;
    }
    float v0 = S, vZ1 = Z9, vZ2 = Z8, vZ3 = Z7;
    float T0, T1, T2, T3, T4, T5;
    { float xx = sx<1>(v0); T0 = (lane&1)? xx-v0 : v0-xx; v0 += xx;
      vZ1 += sx<1>(vZ1); vZ2 += sx<1>(vZ2); vZ3 += sx<1>(vZ3); }
    { float xx = sx<2>(v0); T1 = (lane&2)? xx-v0 : v0-xx; v0 += xx;
      vZ1 += sx<2>(vZ1); vZ2 += sx<2>(vZ2); vZ3 += sx<2>(vZ3);
      T0 += sx<2>(T0); }
    { float xx = __shfl_xor(v0, 4,64); T2 = (lane&4)? xx-v0 : v0-xx; v0 += xx;
      vZ1 += __shfl_xor(vZ1,4,64); vZ2 += __shfl_xor(vZ2,4,64); vZ3 += __shfl_xor(vZ3,4,64);
      T0 += __shfl_xor(T0,4,64); T1 += __shfl_xor(T1,4,64); }
    { float xx = __shfl_xor(v0, 8,64); T3 = (lane&8)? xx-v0 : v0-xx; v0 += xx;
      vZ1 += __shfl_xor(vZ1,8,64); vZ2 += __shfl_xor(vZ2,8,64); vZ3 += __shfl_xor(vZ3,8,64);
      T0 += __shfl_xor(T0,8,64); T1 += __shfl_xor(T1,8,64); T2 += __shfl_xor(T2,8,64); }
    { float xx = __shfl_xor(v0,16,64); T4 = (lane&16)? xx-v0 : v0-xx; v0 += xx;
      vZ1 += __shfl_xor(vZ1,16,64); vZ2 += __shfl_xor(vZ2,16,64); vZ3 += __shfl_xor(vZ3,16,64);
      T0 += __shfl_xor(T0,16,64); T1 += __shfl_xor(T1,16,64); T2 += __shfl_xor(T2,16,64);
      T3 += __shfl_xor(T3,16,64); }
    { float xx = __shfl_xor(v0,32,64); T5 = (lane&32)? xx-v0 : v0-xx; v0 += xx;
      vZ1 += __shfl_xor(vZ1,32,64); vZ2 += __shfl_xor(vZ2,32,64); vZ3 += __shfl_xor(vZ3,32,64);
      T0 += __shfl_xor(T0,32,64); T1 += __shfl_xor(T1,32,64); T2 += __shfl_xor(T2,32,64);
      T3 += __shfl_xor(T3,32,64); T4 += __shfl_xor(T4,32,64); }

    if (lane == 0) {
      float* wr = &wred[w][0];
      wr[0]=v0; wr[1]=vZ1; wr[2]=vZ2; wr[3]=vZ3;
      wr[4]=T0; wr[5]=T1; wr[6]=T2; wr[7]=T3; wr[8]=T4; wr[9]=T5;
    }
    __syncthreads();
    #define SUM4(j) (wred[0][j]+wred[1][j]+wred[2][j]+wred[3][j])
    float P0 = wred[0][0], P1 = wred[1][0], P2 = wred[2][0], P3 = wred[3][0];
    float zb10 = (P0+P1) - (P2+P3);
    float zb0  = (P0+P2) - (P1+P3);
    h0 = zb10; h1 = SUM4(1); h2 = SUM4(2); h3 = SUM4(3); h4 = SUM4(9);
    float o0 = SUM4(8), o1 = SUM4(7), o2 = SUM4(6), o3 = SUM4(5), o4 = SUM4(4), o5 = zb0;
    #undef SUM4

    if (tid == 0) {
      float* op = out + (size_t)b*(TSTEPS*6) + t*6;
      op[0]=o0; op[1]=o1; op[2]=o2; op[3]=o3; op[4]=o4; op[5]=o5;
      if (t == TSTEPS-1) {
        float* hp = out + BATCH*TSTEPS*6 + b*5;
        hp[0]=h0; hp[1]=h1; hp[2]=h2; hp[3]=h3; hp[4]=h4;
      }
    }
    // wred WAR vs next step: protected by the 2 wave-gate barriers
  }
}

extern "C" void kernel_launch(void* const* d_in, const int* in_sizes, int n_in,
                              void* d_out, int out_size, void* d_ws, size_t ws_size,
                              hipStream_t stream) {
  const float* x      = (const float*)d_in[0];
  const float* hidden = (const float*)d_in[1];
  const float* params = (const float*)d_in[2];
  float* out          = (float*)d_out;
  qrnn_kernel<<<dim3(BATCH), dim3(BLOCK), 0, stream>>>(x, hidden, params, out);
}

// Round 4
// 241.315 us; speedup vs baseline: 3.6732x; 1.1088x over previous
//
#include <hip/hip_runtime.h>
#include <math.h>

#define TSTEPS 48
#define FEAT 60
#define BATCH 128
#define BLOCK 512
#define TWO_PI_F 6.2831853071795864769f

// BLOCK=512: 8 waves/block -> 2 waves/SIMD (latency hiding), 4 amps/thread.
// State-bit map (state bit b holds qubit 10-b):
//   b10=l5  b9=r1  b8=r0  b7=l4  b6=l3  b5=l2  b4=l1  b3=l0  b2=w2 b1=w1 b0=w0
// qubits: q0=l5 q1=r1 q2=r0 q3=l4 q4=l3 q5=l2 q6=l1 q7=l0 q8=w2 q9=w1 q10=w0
// Layer-1 1q gates folded into embedding; L1 CRXs local (no barrier).
// Layer-2: q0..q7 local gates (CRX fused, selects loop-invariant per thread);
// q8,q9,q10 merged into ONE 8x8 tensor exchange (1 barrier). 2 barriers/step.

struct Cf { float r, i; };
__device__ __forceinline__ Cf cmul(Cf a, Cf b){ return {a.r*b.r - a.i*b.i, a.r*b.i + a.i*b.r}; }
__device__ __forceinline__ Cf cadd(Cf a, Cf b){ return {a.r+b.r, a.i+b.i}; }
__device__ __forceinline__ void mm2(const Cf A[4], const Cf B[4], Cf D[4]) {
  D[0] = cadd(cmul(A[0],B[0]), cmul(A[1],B[2]));
  D[1] = cadd(cmul(A[0],B[1]), cmul(A[1],B[3]));
  D[2] = cadd(cmul(A[2],B[0]), cmul(A[3],B[2]));
  D[3] = cadd(cmul(A[2],B[1]), cmul(A[3],B[3]));
}

struct Mat { float4 r0, r1; };

__device__ __forceinline__ float rlane(float v, int l) {
  return __int_as_float(__builtin_amdgcn_readlane(__float_as_int(v), l));
}

template<int M>
__device__ __forceinline__ float sx(float v) {
  if constexpr (M == 1)
    return __int_as_float(__builtin_amdgcn_mov_dpp(__float_as_int(v), 0xB1, 0xF, 0xF, true));
  else if constexpr (M == 2)
    return __int_as_float(__builtin_amdgcn_mov_dpp(__float_as_int(v), 0x4E, 0xF, 0xF, true));
  else
    return __shfl_xor(v, M, 64);
}

__device__ __forceinline__ Cf csel(float4 v, int b) {
  return b ? Cf{v.z, v.w} : Cf{v.x, v.y};
}

// row of 2x2 gate for this thread's side: new = m.xy * a + m.zw * partner
__device__ __forceinline__ float4 rowsel(const float* M, int bit) {
  return bit ? make_float4(M[6],M[7],M[4],M[5])
             : make_float4(M[0],M[1],M[2],M[3]);
}

template<int MASK>
__device__ __forceinline__ void lgate(float2& a, float4 m) {
  float px = sx<MASK>(a.x), py = sx<MASK>(a.y);
  float ax = a.x, ay = a.y;
  a.x = m.x*ax - m.y*ay + m.z*px - m.w*py;
  a.y = m.x*ay + m.y*ax + m.z*py + m.w*px;
}

// full 2x2 gate on an in-thread amp pair
__device__ __forceinline__ void rgate(float2& A, float2& B, Mat M) {
  float2 A0 = A, B0 = B;
  A.x = M.r0.x*A0.x - M.r0.y*A0.y + M.r0.z*B0.x - M.r0.w*B0.y;
  A.y = M.r0.x*A0.y + M.r0.y*A0.x + M.r0.z*B0.y + M.r0.w*B0.x;
  B.x = M.r1.x*A0.x - M.r1.y*A0.y + M.r1.z*B0.x - M.r1.w*B0.y;
  B.y = M.r1.x*A0.y + M.r1.y*A0.x + M.r1.z*B0.y + M.r1.w*B0.x;
}

// RX on in-thread pair: a0' = c*a0 - i s*a1 (and symmetric)
__device__ __forceinline__ void rxmix(float2& a0, float2& a1, float c, float s) {
  float n0x = c*a0.x + s*a1.y, n0y = c*a0.y - s*a1.x;
  float n1x = c*a1.x + s*a0.y, n1y = c*a1.y - s*a0.x;
  a0.x = n0x; a0.y = n0y; a1.x = n1x; a1.y = n1y;
}

// RX across a lane bit (matrix symmetric: same formula both sides)
template<int MASK>
__device__ __forceinline__ void rxs(float2& a, float c, float s) {
  float px = sx<MASK>(a.x), py = sx<MASK>(a.y);
  float ax = a.x, ay = a.y;
  a.x = c*ax + s*py;
  a.y = c*ay - s*px;
}

__global__ __launch_bounds__(BLOCK, 2)
void qrnn_kernel(const float* __restrict__ x, const float* __restrict__ hin,
                 const float* __restrict__ params, float* __restrict__ out) {
  const int b    = blockIdx.x;
  const int tid  = threadIdx.x;
  const int lane = tid & 63;
  const int w    = tid >> 6;                   // 0..7
  const int l5 = (lane>>5)&1, l4=(lane>>4)&1, l3=(lane>>3)&1,
            l2 = (lane>>2)&1, l1=(lane>>1)&1, l0=lane&1;

  __shared__ __align__(16) float matU[2][11][8];
  __shared__ __align__(16) float matVs[4][8];      // L2 CRX-fused: V=RX*U2[i+1]
  __shared__ float  xs[TSTEPS*FEAT];
  __shared__ float  pooled[TSTEPS][6];
  __shared__ float4 evis[TSTEPS][6];               // visible e-vecs (q5..q10)
  __shared__ __align__(16) float4 xbuf[8*64*2];    // merge exchange, 16 KB
  __shared__ float  wred[8][12];

  // ---- stage x ----
  for (int j = tid; j < TSTEPS*FEAT; j += BLOCK)
    xs[j] = x[(size_t)b*TSTEPS*FEAT + j];
  // ---- fused per-(layer,qubit) U = RZ*RY*RX ----
  if (tid < 22) {
    int l = tid / 11, k = tid % 11;
    int base = 37 * l;
    int off = (k < 5) ? (base + 3*k) : (base + 19 + 3*(k-5));
    float px = params[off], py = params[off+1], pz = params[off+2];
    float cx = cosf(0.5f*px), sxn = sinf(0.5f*px);
    float cy = cosf(0.5f*py), syn = sinf(0.5f*py);
    float cz = cosf(0.5f*pz), szn = sinf(0.5f*pz);
    Cf RX[4] = {{cx,0.f},{0.f,-sxn},{0.f,-sxn},{cx,0.f}};
    Cf RY[4] = {{cy,0.f},{-syn,0.f},{syn,0.f},{cy,0.f}};
    Cf RZ[4] = {{cz,-szn},{0.f,0.f},{0.f,0.f},{cz,szn}};
    Cf M[4], U[4];
    mm2(RY, RX, M);
    mm2(RZ, M,  U);
    float* d = &matU[l][k][0];
    d[0]=U[0].r; d[1]=U[0].i; d[2]=U[1].r; d[3]=U[1].i;
    d[4]=U[2].r; d[5]=U[2].i; d[6]=U[3].r; d[7]=U[3].i;
  }
  __syncthreads();
  if (tid < 4) {                                   // V[i] = RX(th_L2,i)*U2[i+1]
    float th = params[37 + 15 + tid];
    float c = cosf(0.5f*th), s = sinf(0.5f*th);
    const float* Up = &matU[1][tid+1][0];
    Cf U00{Up[0],Up[1]}, U01{Up[2],Up[3]}, U10{Up[4],Up[5]}, U11{Up[6],Up[7]};
    Cf ms{0.f, -s};
    Cf V00 = cadd(Cf{c*U00.r, c*U00.i}, cmul(ms, U10));
    Cf V01 = cadd(Cf{c*U01.r, c*U01.i}, cmul(ms, U11));
    Cf V10 = cadd(cmul(ms, U00), Cf{c*U10.r, c*U10.i});
    Cf V11 = cadd(cmul(ms, U01), Cf{c*U11.r, c*U11.i});
    float* d = &matVs[tid][0];
    d[0]=V00.r; d[1]=V00.i; d[2]=V01.r; d[3]=V01.i;
    d[4]=V10.r; d[5]=V10.i; d[6]=V11.r; d[7]=V11.i;
  }
  for (int j = tid; j < TSTEPS*6; j += BLOCK) {    // window means
    int t = j / 6, k = j % 6;
    const float* xp = &xs[t*FEAT + k*10];
    float s = 0.f;
    #pragma unroll
    for (int f = 0; f < 10; ++f) s += xp[f];
    pooled[t][k] = s * 0.1f;
  }
  __syncthreads();
  for (int j = tid; j < TSTEPS*6; j += BLOCK) {    // visible e-vectors
    int t = j / 6, k = j % 6;
    float mn = pooled[t][0], mx = pooled[t][0];
    #pragma unroll
    for (int v = 1; v < 6; ++v) { mn = fminf(mn, pooled[t][v]); mx = fmaxf(mx, pooled[t][v]); }
    float ang = TWO_PI_F * (pooled[t][k] - mn) / (mx - mn + 1e-8f);
    float c = __cosf(0.5f*ang), s = __sinf(0.5f*ang);
    const float* U = &matU[0][5+k][0];
    evis[t][k] = make_float4(U[0]*c + U[3]*s, U[1]*c - U[2]*s,
                             U[4]*c + U[7]*s, U[5]*c - U[6]*s);
  }

  // ---- per-thread loop-invariant gate data (all selects by fixed lane bits) ----
  Mat Mq1;                                          // q1 reg-gate, ctrl q0=l5
  { const float* p = l5 ? &matVs[0][0] : &matU[1][1][0];
    Mq1.r0 = *(const float4*)p; Mq1.r1 = *(const float4*)(p+4); }
  Mat Mq2a, Mq2b;                                   // q2 reg-gate, ctrl q1=r1
  Mq2a.r0 = *(const float4*)&matU[1][2][0]; Mq2a.r1 = *(const float4*)&matU[1][2][4];
  Mq2b.r0 = *(const float4*)&matVs[1][0];   Mq2b.r1 = *(const float4*)&matVs[1][4];
  float4 q0row  = rowsel(&matU[1][0][0], l5);
  float4 q3rowU = rowsel(&matU[1][3][0], l4);       // amps r0=0
  float4 q3rowV = rowsel(&matVs[2][0],   l4);       // amps r0=1 (ctrl q2=r0)
  float4 q4row  = rowsel(l4 ? &matVs[3][0] : &matU[1][4][0], l3);  // ctrl q3=l4
  float4 q5row  = rowsel(&matU[1][5][0], l2);
  float4 q6row  = rowsel(&matU[1][6][0], l1);
  float4 q7row  = rowsel(&matU[1][7][0], l0);
  // L1 CRX trig (control blends fixed per thread)
  float c1p, s1p, c2v, s2v, c3v, s3v, c4p, s4p;
  { float th = params[15]; float c = cosf(0.5f*th), s = sinf(0.5f*th);
    c1p = l5 ? c : 1.f; s1p = l5 ? s : 0.f; }       // ctrl q0=l5
  { float th = params[16]; c2v = cosf(0.5f*th); s2v = sinf(0.5f*th); }
  { float th = params[17]; c3v = cosf(0.5f*th); s3v = sinf(0.5f*th); }
  { float th = params[18]; float c = cosf(0.5f*th), s = sinf(0.5f*th);
    c4p = l4 ? c : 1.f; s4p = l4 ? s : 0.f; }       // ctrl q3=l4
  // merge coefficients: row of U2[8] (x) U2[9] (x) U2[10] for this wave,
  // stored XOR-indexed: d[k] = coef(source combo w^k)
  float dR[8], dI[8];
  { const int i2 = (w>>2)&1, i1 = (w>>1)&1, i0 = w&1;
    const float* u8  = &matU[1][8][0];
    const float* u9  = &matU[1][9][0];
    const float* u10 = &matU[1][10][0];
    #pragma unroll
    for (int k = 0; k < 8; ++k) {
      int j = w ^ k;
      int j2 = (j>>2)&1, j1 = (j>>1)&1, j0 = j&1;
      Cf a8 {u8 [(i2*2+j2)*2], u8 [(i2*2+j2)*2+1]};
      Cf a9 {u9 [(i1*2+j1)*2], u9 [(i1*2+j1)*2+1]};
      Cf a10{u10[(i0*2+j0)*2], u10[(i0*2+j0)*2+1]};
      Cf c = cmul(cmul(a8, a9), a10);
      dR[k] = c.r; dI[k] = c.i;
    }
  }
  // U1 hidden-trio row matrices for lanes 0..4 (lane q handles hidden qubit q)
  const int lq = (lane < 5) ? lane : 0;
  float4 mH0 = *(const float4*)&matU[0][lq][0];
  float4 mH1 = *(const float4*)&matU[0][lq][4];
  float hreg = (lane < 5) ? hin[b*5 + lane] : 0.f;
  __syncthreads();

  #pragma unroll 1
  for (int t = 0; t < TSTEPS; ++t) {
    // ---- visible embed factor ----
    float4 v5 = evis[t][0], v6 = evis[t][1], v7 = evis[t][2],
           v8 = evis[t][3], v9 = evis[t][4], v10 = evis[t][5];
    Cf Fv = csel(v8, (w>>2)&1);                    // q8 = w2
    Fv = cmul(Fv, csel(v9, (w>>1)&1));             // q9 = w1
    Fv = cmul(Fv, csel(v10, w&1));                 // q10 = w0
    Fv = cmul(Fv, csel(v5, l2));                   // q5
    Fv = cmul(Fv, csel(v6, l1));                   // q6
    Fv = cmul(Fv, csel(v7, l0));                   // q7

    // ---- hidden e-vectors (lanes 0..4 compute, readlane broadcast) ----
    float chh = __cosf(0.5f*hreg), shh = __sinf(0.5f*hreg);
    float e0r_ = mH0.x*chh + mH0.w*shh;
    float e0i_ = mH0.y*chh - mH0.z*shh;
    float e1r_ = mH1.x*chh + mH1.w*shh;
    float e1i_ = mH1.y*chh - mH1.z*shh;
    Cf Eq0, Eq3, Eq4, E1[2], E2[2];
    { float A=rlane(e0r_,0), B=rlane(e0i_,0), C=rlane(e1r_,0), D=rlane(e1i_,0);
      Eq0 = { l5 ? C : A, l5 ? D : B }; }
    { float A=rlane(e0r_,3), B=rlane(e0i_,3), C=rlane(e1r_,3), D=rlane(e1i_,3);
      Eq3 = { l4 ? C : A, l4 ? D : B }; }
    { float A=rlane(e0r_,4), B=rlane(e0i_,4), C=rlane(e1r_,4), D=rlane(e1i_,4);
      Eq4 = { l3 ? C : A, l3 ? D : B }; }
    E1[0] = { rlane(e0r_,1), rlane(e0i_,1) };
    E1[1] = { rlane(e1r_,1), rlane(e1i_,1) };
    E2[0] = { rlane(e0r_,2), rlane(e0i_,2) };
    E2[1] = { rlane(e1r_,2), rlane(e1i_,2) };

    // ---- embed (L1 1q gates folded) ----
    Cf F = cmul(cmul(Fv, Eq0), cmul(Eq3, Eq4));
    float2 a[4];
    #pragma unroll
    for (int r = 0; r < 4; ++r) {
      Cf P = cmul(E1[(r>>1)&1], E2[r&1]);
      Cf A = cmul(F, P);
      a[r].x = A.r; a[r].y = A.i;
    }

    // ---- layer 1 CRXs (all local) ----
    rxmix(a[0], a[2], c1p, s1p);                   // CRX(q0,q1): tgt r1
    rxmix(a[1], a[3], c1p, s1p);
    rxmix(a[2], a[3], c2v, s2v);                   // CRX(q1,q2): ctrl r1, tgt r0
    rxs<16>(a[1], c3v, s3v);                       // CRX(q2,q3): ctrl r0, tgt l4
    rxs<16>(a[3], c3v, s3v);
    rxs<8>(a[0], c4p, s4p);                        // CRX(q3,q4): ctrl l4, tgt l3
    rxs<8>(a[1], c4p, s4p);
    rxs<8>(a[2], c4p, s4p);
    rxs<8>(a[3], c4p, s4p);

    // ---- layer 2: q0..q7 local ----
    lgate<32>(a[0], q0row); lgate<32>(a[1], q0row);
    lgate<32>(a[2], q0row); lgate<32>(a[3], q0row);
    rgate(a[0], a[2], Mq1);                        // q1 (+CRX c=q0 via Mq1)
    rgate(a[1], a[3], Mq1);
    rgate(a[0], a[1], Mq2a);                       // q2 (+CRX c=q1)
    rgate(a[2], a[3], Mq2b);
    lgate<16>(a[0], q3rowU); lgate<16>(a[2], q3rowU);  // q3 (+CRX c=q2)
    lgate<16>(a[1], q3rowV); lgate<16>(a[3], q3rowV);
    lgate<8>(a[0], q4row);  lgate<8>(a[1], q4row);     // q4 (+CRX c=q3)
    lgate<8>(a[2], q4row);  lgate<8>(a[3], q4row);
    lgate<4>(a[0], q5row);  lgate<4>(a[1], q5row);
    lgate<4>(a[2], q5row);  lgate<4>(a[3], q5row);
    lgate<2>(a[0], q6row);  lgate<2>(a[1], q6row);     // DPP
    lgate<2>(a[2], q6row);  lgate<2>(a[3], q6row);
    lgate<1>(a[0], q7row);  lgate<1>(a[1], q7row);     // DPP
    lgate<1>(a[2], q7row);  lgate<1>(a[3], q7row);

    // ---- layer 2: q8,q9,q10 merged 8x8 exchange (1 barrier) ----
    {
      const int base = ((w<<6) + lane) * 2;
      xbuf[base]   = make_float4(a[0].x, a[0].y, a[1].x, a[1].y);
      xbuf[base+1] = make_float4(a[2].x, a[2].y, a[3].x, a[3].y);
      __syncthreads();
      float2 n[4];
      #pragma unroll
      for (int r = 0; r < 4; ++r) {
        n[r].x = dR[0]*a[r].x - dI[0]*a[r].y;
        n[r].y = dR[0]*a[r].y + dI[0]*a[r].x;
      }
      #pragma unroll
      for (int k = 1; k < 8; ++k) {
        const int j = w ^ k;
        float4 p01 = xbuf[((j<<6) + lane)*2];
        float4 p23 = xbuf[((j<<6) + lane)*2 + 1];
        n[0].x += dR[k]*p01.x - dI[k]*p01.y; n[0].y += dR[k]*p01.y + dI[k]*p01.x;
        n[1].x += dR[k]*p01.z - dI[k]*p01.w; n[1].y += dR[k]*p01.w + dI[k]*p01.z;
        n[2].x += dR[k]*p23.x - dI[k]*p23.y; n[2].y += dR[k]*p23.y + dI[k]*p23.x;
        n[3].x += dR[k]*p23.z - dI[k]*p23.w; n[3].y += dR[k]*p23.w + dI[k]*p23.z;
      }
      a[0] = n[0]; a[1] = n[1]; a[2] = n[2]; a[3] = n[3];
    }

    // ---- <Z>: per-thread partials + signed butterfly over 6 lane bits ----
    float p0 = a[0].x*a[0].x + a[0].y*a[0].y;
    float p1 = a[1].x*a[1].x + a[1].y*a[1].y;
    float p2 = a[2].x*a[2].x + a[2].y*a[2].y;
    float p3 = a[3].x*a[3].x + a[3].y*a[3].y;
    float S  = p0+p1+p2+p3;
    float Z1 = (p0+p1)-(p2+p3);                    // q1 (r1)
    float Z2 = (p0-p1)+(p2-p3);                    // q2 (r0)
    float T0,T1,T2,T3,T4,T5;
    { float xx=sx<1>(S);  T0=(lane&1) ? xx-S : S-xx; S+=xx;
      Z1+=sx<1>(Z1); Z2+=sx<1>(Z2); }
    { float xx=sx<2>(S);  T1=(lane&2) ? xx-S : S-xx; S+=xx;
      Z1+=sx<2>(Z1); Z2+=sx<2>(Z2); T0+=sx<2>(T0); }
    { float xx=sx<4>(S);  T2=(lane&4) ? xx-S : S-xx; S+=xx;
      Z1+=sx<4>(Z1); Z2+=sx<4>(Z2); T0+=sx<4>(T0); T1+=sx<4>(T1); }
    { float xx=sx<8>(S);  T3=(lane&8) ? xx-S : S-xx; S+=xx;
      Z1+=sx<8>(Z1); Z2+=sx<8>(Z2); T0+=sx<8>(T0); T1+=sx<8>(T1); T2+=sx<8>(T2); }
    { float xx=sx<16>(S); T4=(lane&16)? xx-S : S-xx; S+=xx;
      Z1+=sx<16>(Z1); Z2+=sx<16>(Z2); T0+=sx<16>(T0); T1+=sx<16>(T1);
      T2+=sx<16>(T2); T3+=sx<16>(T3); }
    { float xx=sx<32>(S); T5=(lane&32)? xx-S : S-xx; S+=xx;
      Z1+=sx<32>(Z1); Z2+=sx<32>(Z2); T0+=sx<32>(T0); T1+=sx<32>(T1);
      T2+=sx<32>(T2); T3+=sx<32>(T3); T4+=sx<32>(T4); }
    if (lane == 0) {
      float* wr = &wred[w][0];
      wr[0]=S; wr[1]=Z1; wr[2]=Z2;
      wr[3]=T0; wr[4]=T1; wr[5]=T2; wr[6]=T3; wr[7]=T4; wr[8]=T5;
    }
    __syncthreads();

    // hidden z (lanes 0..4, every wave): q0->T5(8) q1->Z1(1) q2->Z2(2)
    //                                    q3->T4(7) q4->T3(6)
    if (lane < 5) {
      int slot = (lane==0) ? 8 : (lane==1) ? 1 : (lane==2) ? 2 : (lane==3) ? 7 : 6;
      float z = 0.f;
      #pragma unroll
      for (int ww = 0; ww < 8; ++ww) z += wred[ww][slot];
      hreg = z;
      if (t == TSTEPS-1 && w == 0)
        out[BATCH*TSTEPS*6 + b*5 + lane] = z;
    }
    // outputs (wave 0, lanes 5..10): q5->T2(5) q6->T1(4) q7->T0(3),
    // q8/q9/q10 from S with wave-bit signs
    if (w == 0 && lane >= 5 && lane < 11) {
      float z = 0.f;
      if (lane < 8) {
        int slot = (lane==5) ? 5 : (lane==6) ? 4 : 3;
        #pragma unroll
        for (int ww = 0; ww < 8; ++ww) z += wred[ww][slot];
      } else {
        int wb = (lane==8) ? 4 : (lane==9) ? 2 : 1;
        #pragma unroll
        for (int ww = 0; ww < 8; ++ww)
          z += (ww & wb) ? -wred[ww][0] : wred[ww][0];
      }
      out[(size_t)b*TSTEPS*6 + t*6 + (lane-5)] = z;
    }
    // hazards: this step's wred reads precede next step's wred writes via the
    // next merge barrier; xbuf WAR protected by the wred barrier above.
  }
}

extern "C" void kernel_launch(void* const* d_in, const int* in_sizes, int n_in,
                              void* d_out, int out_size, void* d_ws, size_t ws_size,
                              hipStream_t stream) {
  const float* x      = (const float*)d_in[0];
  const float* hidden = (const float*)d_in[1];
  const float* params = (const float*)d_in[2];
  float* out          = (float*)d_out;
  qrnn_kernel<<<dim3(BATCH), dim3(BLOCK), 0, stream>>>(x, hidden, params, out);
}